// Round 21
// baseline (99.469 us; speedup 1.0000x reference)
//
#include <hip/hip_runtime.h>
#include <math.h>

#define D_MODEL 1024
#define HEAD 64
#define BATCH 4
#define SEQ 2048
#define M_TOT (BATCH*SEQ)   // 8192

typedef short short8 __attribute__((ext_vector_type(8)));
typedef float f32x4 __attribute__((ext_vector_type(4)));
typedef unsigned short ushort_t;

typedef const __attribute__((address_space(1))) char* gas_t;
typedef __attribute__((address_space(3))) char* las_t;
#define GLDS16(src, dst) __builtin_amdgcn_global_load_lds((gas_t)(const void*)(src), (las_t)(void*)(dst), 16, 0, 0)

__device__ __forceinline__ unsigned short f2bf(float x) {       // round-to-nearest
    union { float f; unsigned u; } v; v.f = x;
    unsigned r = (v.u + 0x7FFFu + ((v.u >> 16) & 1u)) >> 16;
    return (unsigned short)r;
}
__device__ __forceinline__ unsigned short f2bf_trunc(float x) { // truncate mantissa
    union { float f; unsigned u; } v; v.f = x;
    return (unsigned short)(v.u >> 16);
}
__device__ __forceinline__ float bf2f(unsigned short h) {
    union { unsigned u; float f; } v; v.u = ((unsigned)h) << 16;
    return v.f;
}

// ---------------- W split prep (unchanged) ----------------
__global__ __launch_bounds__(256) void wsplit_kernel(
    const float* __restrict__ wq, const float* __restrict__ wk,
    const float* __restrict__ wv,
    ushort_t* __restrict__ Wfhi, ushort_t* __restrict__ Wflo)
{
    int tid = blockIdx.x * 256 + threadIdx.x;      // 0..24575
    int l = tid & 63;
    int c = l & 15, g = l >> 4;
    int rest = tid >> 6;
    int nt = rest % 12, ks = rest / 12;
    const float* W = (nt < 4) ? wq : ((nt < 8) ? wk : wv);
    int colm = ((nt & 3) * 16) + c;
    short8 hi, lo;
#pragma unroll
    for (int e = 0; e < 8; ++e) {
        float v = W[(size_t)(32 * ks + 8 * g + e) * HEAD + colm];
        unsigned short h = f2bf_trunc(v);
        hi[e] = (short)h;
        lo[e] = (short)f2bf(v - bf2f(h));
    }
    *(short8*)&Wfhi[(size_t)tid * 8] = hi;
    *(short8*)&Wflo[(size_t)tid * 8] = lo;
}

// ---------------- QKV projection v6: glds pipeline, nt-pair jobs, depth-3 --
// Job = (m-tile, nt-pair): wave computes 2 x 16-col tiles of one 16-row
// m-tile. 3072 jobs / 768 blocks. Per k-step: 6 glds (x fp32 2KB + W hi/lo
// 4KB) into a 6KB slot; 3 slots/wave (72KB/block, 2 blocks/CU) -> lookahead
// = 2 k-steps (~360cyc) >= L2 latency, so vmcnt(12) is satisfied in steady
// state. R19 (depth-2, 8KB slots) left ~half the latency exposed.
__global__ __launch_bounds__(256) void proj_kernel(
    const float* __restrict__ x,
    const ushort_t* __restrict__ Wfhi, const ushort_t* __restrict__ Wflo,
    const float* __restrict__ bq, const float* __restrict__ bk,
    const float* __restrict__ bv,
    ushort_t* __restrict__ Qhi, ushort_t* __restrict__ Qlo,
    float* __restrict__ Kw, ushort_t* __restrict__ Vt)
{
    __shared__ __align__(16) char pbuf[73728];   // 4 waves x 3 slots x 6 KB

    const int t = threadIdx.x;
    const int w = t >> 6;
    const int l = t & 63;
    const int c = l & 15, g = l >> 4;
    const int job = blockIdx.x * 4 + w;
    const int mt = job / 6;
    const int pair = job - mt * 6;      // 0..5 -> nt {2p, 2p+1}
    const int m0 = mt * 16;

    char* wbase = pbuf + w * 18432;

    f32x4 acc0 = (f32x4)0.0f, acc1 = (f32x4)0.0f;
    const float* xsrc = &x[(size_t)(m0 + c) * D_MODEL + 8 * g];

    // slot layout (6KB): [0,1K) xA [1K,2K) xB [2K,3K) W0hi [3K,4K) W0lo
    //                    [4K,5K) W1hi [5K,6K) W1lo
#define STAGE(i)                                                              \
    do {                                                                      \
        char* sb = wbase + ((i) % 3) * 6144;                                  \
        const float* xa = xsrc + (i) * 32;                                    \
        GLDS16(xa, sb);                                                       \
        GLDS16(xa + 4, sb + 1024);                                            \
        const size_t wo0 = ((size_t)(i) * 12 + 2 * pair) * 512 + l * 8;       \
        GLDS16(&Wfhi[wo0], sb + 2048);                                        \
        GLDS16(&Wflo[wo0], sb + 3072);                                        \
        GLDS16(&Wfhi[wo0 + 512], sb + 4096);                                  \
        GLDS16(&Wflo[wo0 + 512], sb + 5120);                                  \
    } while (0)

    STAGE(0);
    STAGE(1);
    STAGE(2);

#pragma unroll 1
    for (int i = 0; i < 32; ++i) {
        if (i < 30)       asm volatile("s_waitcnt vmcnt(12)" ::: "memory");
        else if (i == 30) asm volatile("s_waitcnt vmcnt(6)" ::: "memory");
        else              asm volatile("s_waitcnt vmcnt(0)" ::: "memory");
        __builtin_amdgcn_sched_barrier(0);
        char* sb = wbase + (i % 3) * 6144;
        float4 fa = *(const float4*)(sb + l * 16);
        float4 fb = *(const float4*)(sb + 1024 + l * 16);
        float xs8[8] = {fa.x, fa.y, fa.z, fa.w, fb.x, fb.y, fb.z, fb.w};
        short8 xh, xl;
#pragma unroll
        for (int e = 0; e < 8; ++e) {
            unsigned short h = f2bf_trunc(xs8[e]);
            xh[e] = (short)h;
            xl[e] = (short)f2bf(xs8[e] - bf2f(h));
        }
        short8 wh0 = *(const short8*)(sb + 2048 + l * 16);
        short8 wl0 = *(const short8*)(sb + 3072 + l * 16);
        short8 wh1 = *(const short8*)(sb + 4096 + l * 16);
        short8 wl1 = *(const short8*)(sb + 5120 + l * 16);
        acc0 = __builtin_amdgcn_mfma_f32_16x16x32_bf16(xh, wh0, acc0, 0, 0, 0);
        acc0 = __builtin_amdgcn_mfma_f32_16x16x32_bf16(xl, wh0, acc0, 0, 0, 0);
        acc0 = __builtin_amdgcn_mfma_f32_16x16x32_bf16(xh, wl0, acc0, 0, 0, 0);
        acc1 = __builtin_amdgcn_mfma_f32_16x16x32_bf16(xh, wh1, acc1, 0, 0, 0);
        acc1 = __builtin_amdgcn_mfma_f32_16x16x32_bf16(xl, wh1, acc1, 0, 0, 0);
        acc1 = __builtin_amdgcn_mfma_f32_16x16x32_bf16(xh, wl1, acc1, 0, 0, 0);
        if (i < 29) STAGE(i + 3);
    }
#undef STAGE

    // epilogue: per-wave, aliased into the idle pipeline LDS region
    float* eldw = (float*)wbase;            // [2][16][17]
#define ELD(j, r, cc) eldw[((j) * 16 + (r)) * 17 + (cc)]
    {
        f32x4 a[2] = {acc0, acc1};
#pragma unroll
        for (int j = 0; j < 2; ++j)
#pragma unroll
            for (int r = 0; r < 4; ++r)
                ELD(j, 4 * g + r, c) = a[j][r];
    }

    const int b = m0 >> 11;
    const int s0 = m0 & 2047;

#pragma unroll
    for (int j = 0; j < 2; ++j) {
        const int nt = 2 * pair + j;
        const int col16 = (nt & 3) * 16;
        if (nt < 4) {
            const int row = l >> 2, cc4 = (l & 3) * 4;
            unsigned hu[2] = {0, 0}, lu[2] = {0, 0};
#pragma unroll
            for (int i = 0; i < 4; ++i) {
                float v = (ELD(j, row, cc4 + i) + bq[col16 + cc4 + i]) * 8.0f;
                unsigned short h = f2bf_trunc(v);
                unsigned short lo2 = f2bf(v - bf2f(h));
                hu[i >> 1] |= ((unsigned)h) << ((i & 1) * 16);
                lu[i >> 1] |= ((unsigned)lo2) << ((i & 1) * 16);
            }
            size_t off = (size_t)(m0 + row) * HEAD + col16 + cc4;
            *(uint2*)&Qhi[off] = make_uint2(hu[0], hu[1]);
            *(uint2*)&Qlo[off] = make_uint2(lu[0], lu[1]);
        } else if (nt < 8) {
            const int row = l >> 2, cc4 = (l & 3) * 4;
            float4 o;
            o.x = ELD(j, row, cc4 + 0) + bk[col16 + cc4 + 0];
            o.y = ELD(j, row, cc4 + 1) + bk[col16 + cc4 + 1];
            o.z = ELD(j, row, cc4 + 2) + bk[col16 + cc4 + 2];
            o.w = ELD(j, row, cc4 + 3) + bk[col16 + cc4 + 3];
            *(float4*)&Kw[(size_t)(m0 + row) * HEAD + col16 + cc4] = o;
        } else {
            const int dl = l >> 2, sg = (l & 3) * 4;
            const float bb = bv[col16 + dl];
            unsigned vu[2] = {0, 0};
#pragma unroll
            for (int i = 0; i < 4; ++i) {
                unsigned short v = f2bf(ELD(j, sg + i, dl) + bb);
                vu[i >> 1] |= ((unsigned)v) << ((i & 1) * 16);
            }
            *(uint2*)&Vt[((size_t)b * HEAD + col16 + dl) * SEQ + s0 + sg] =
                make_uint2(vu[0], vu[1]);
        }
    }
#undef ELD
}

// ---------------- Flash causal attention v8 (unchanged from R18) -----------
#define NW 4
#define CHUNK 16
#define PSTR 72
#define NSEG 4          // segments of 512 kv positions (8 tiles)

__global__ __launch_bounds__(256) void attn_part_kernel(
    const ushort_t* __restrict__ Qhi, const ushort_t* __restrict__ Qlo,
    const float* __restrict__ Kw, const ushort_t* __restrict__ Vt,
    float* __restrict__ Pm_ws, float* __restrict__ Pl_ws,
    float* __restrict__ Po_ws)
{
    __shared__ float Po[NW][CHUNK][68];
    __shared__ float Pm[NW][CHUNK];
    __shared__ float Pl[NW][CHUNK];
    __shared__ __align__(16) ushort_t Plds[NW][CHUNK][PSTR];

    const int t = threadIdx.x;
    const int w = t >> 6;
    const int l = t & 63;
    int id = blockIdx.x;
    int seg, base;
    if (id < 128)      { seg = 0; base = 0;   }
    else if (id < 224) { seg = 1; base = 128; }
    else if (id < 288) { seg = 2; base = 224; }
    else               { seg = 3; base = 288; }
    const int chunk = 127 - (id - base);
    const int b = blockIdx.y;
    const int q0 = chunk * CHUNK;

    const int c = l & 15;
    const int g = l >> 4;

    short8 qhi[2], qlo[2];
    {
        const ushort_t* qbase = &Qhi[(size_t)(b * SEQ + q0 + c) * HEAD];
        const ushort_t* qbasel = &Qlo[(size_t)(b * SEQ + q0 + c) * HEAD];
#pragma unroll
        for (int dc = 0; dc < 2; ++dc) {
            qhi[dc] = *(const short8*)&qbase[dc * 32 + 8 * g];
            qlo[dc] = *(const short8*)&qbasel[dc * 32 + 8 * g];
        }
    }

    f32x4 acc[4];
#pragma unroll
    for (int dt = 0; dt < 4; ++dt) acc[dt] = (f32x4)0.0f;
    float mrun = -1e30f, lsum = 0.f;

#pragma unroll 1
    for (int i = 0; i < 2; ++i) {
        const int tl = seg * 8 + w + 4 * i;
        const int c0 = tl * 64;
        if (c0 > q0 + CHUNK - 1) continue;

        int nlive = ((q0 + 15 - c0) >> 4) + 1;
        nlive = nlive > 4 ? 4 : nlive;

        float sc[4][4];
        float tmax = -1e30f;
#pragma unroll
        for (int t4 = 0; t4 < 4; ++t4) {
            if (t4 < nlive) {
                f32x4 st = (f32x4)0.0f;
#pragma unroll
                for (int dc = 0; dc < 2; ++dc) {
                    const float* kp = &Kw[(size_t)(b * SEQ + c0 + 16 * t4 + c) * HEAD + dc * 32 + 8 * g];
                    float4 a = *(const float4*)kp;
                    float4 b2 = *(const float4*)(kp + 4);
                    float ks8[8] = {a.x, a.y, a.z, a.w, b2.x, b2.y, b2.z, b2.w};
                    short8 khi, klo;
#pragma unroll
                    for (int e = 0; e < 8; ++e) {
                        unsigned short h = f2bf(ks8[e]);
                        khi[e] = (short)h;
                        klo[e] = (short)f2bf(ks8[e] - bf2f(h));
                    }
                    st = __builtin_amdgcn_mfma_f32_16x16x32_bf16(khi, qhi[dc], st, 0, 0, 0);
                    st = __builtin_amdgcn_mfma_f32_16x16x32_bf16(khi, qlo[dc], st, 0, 0, 0);
                    st = __builtin_amdgcn_mfma_f32_16x16x32_bf16(klo, qhi[dc], st, 0, 0, 0);
                }
#pragma unroll
                for (int r = 0; r < 4; ++r) {
                    int kv = c0 + 16 * t4 + 4 * g + r;
                    float s = (kv <= q0 + c) ? st[r] : -1e30f;
                    sc[t4][r] = s;
                    tmax = fmaxf(tmax, s);
                }
            } else {
#pragma unroll
                for (int r = 0; r < 4; ++r) sc[t4][r] = -1e30f;
            }
        }
        tmax = fmaxf(tmax, __shfl_xor(tmax, 16));
        tmax = fmaxf(tmax, __shfl_xor(tmax, 32));
        float newm = fmaxf(mrun, tmax);
        float corr = __expf(mrun - newm);
        mrun = newm;

        float psum = 0.f;
#pragma unroll
        for (int t4 = 0; t4 < 4; ++t4) {
            if (t4 < nlive) {
#pragma unroll
                for (int r = 0; r < 4; ++r) {
                    float pp = __expf(sc[t4][r] - newm);
                    sc[t4][r] = pp;
                    psum += pp;
                }
            } else {
#pragma unroll
                for (int r = 0; r < 4; ++r) sc[t4][r] = 0.f;
            }
        }
        psum += __shfl_xor(psum, 16);
        psum += __shfl_xor(psum, 32);
        lsum = lsum * corr + psum;

#pragma unroll
        for (int r = 0; r < 4; ++r) {
            float cq = __shfl(corr, 4 * g + r);
#pragma unroll
            for (int dt = 0; dt < 4; ++dt) acc[dt][r] *= cq;
        }

#pragma unroll
        for (int t4 = 0; t4 < 4; ++t4) {
            uint2 u;
            u.x = (unsigned)f2bf(sc[t4][0]) | ((unsigned)f2bf(sc[t4][1]) << 16);
            u.y = (unsigned)f2bf(sc[t4][2]) | ((unsigned)f2bf(sc[t4][3]) << 16);
            *(uint2*)&Plds[w][c][16 * t4 + 4 * g] = u;
        }
        const int nkvc = (nlive + 1) >> 1;
#pragma unroll
        for (int kvc = 0; kvc < 2; ++kvc) {
            if (kvc < nkvc) {
                short8 pf = *(short8*)&Plds[w][c][kvc * 32 + 8 * g];
#pragma unroll
                for (int dt = 0; dt < 4; ++dt) {
                    const ushort_t* vp =
                        &Vt[((size_t)(b * HEAD) + 16 * dt + c) * SEQ + c0 + kvc * 32 + 8 * g];
                    short8 vf = *(const short8*)vp;
                    acc[dt] = __builtin_amdgcn_mfma_f32_16x16x32_bf16(pf, vf, acc[dt], 0, 0, 0);
                }
            }
        }
    }

    if (g == 0) { Pm[w][c] = mrun; Pl[w][c] = lsum; }
#pragma unroll
    for (int dt = 0; dt < 4; ++dt)
#pragma unroll
        for (int r = 0; r < 4; ++r)
            Po[w][4 * g + r][16 * dt + c] = acc[dt][r];
    __syncthreads();

    const int mr = t >> 4;
    const int md = (t & 15) * 4;
    float M = Pm[0][mr];
#pragma unroll
    for (int ww = 1; ww < NW; ++ww) M = fmaxf(M, Pm[ww][mr]);
    float L = 0.f;
    float4 O; O.x = O.y = O.z = O.w = 0.f;
#pragma unroll
    for (int ww = 0; ww < NW; ++ww) {
        float f = __expf(Pm[ww][mr] - M);
        L += f * Pl[ww][mr];
        float4 p = *(const float4*)&Po[ww][mr][md];
        O.x += f * p.x; O.y += f * p.y; O.z += f * p.z; O.w += f * p.w;
    }
    const size_t part = ((size_t)(b * 128 + chunk)) * NSEG + seg;
    *(float4*)&Po_ws[(part * CHUNK + mr) * HEAD + md] = O;
    if ((t & 15) == 0) {
        Pm_ws[part * CHUNK + mr] = M;
        Pl_ws[part * CHUNK + mr] = L;
    }
}

__global__ __launch_bounds__(256) void attn_merge_kernel(
    const float* __restrict__ Pm_ws, const float* __restrict__ Pl_ws,
    const float* __restrict__ Po_ws, float* __restrict__ out)
{
    const int t = threadIdx.x;
    const int chunk = blockIdx.x;
    const int b = blockIdx.y;
    const int nparts = (chunk >> 5) + 1;
    const int mr = t >> 4;
    const int md = (t & 15) * 4;
    const size_t pbase = ((size_t)(b * 128 + chunk)) * NSEG;

    float M = -1e30f;
#pragma unroll 1
    for (int p = 0; p < nparts; ++p)
        M = fmaxf(M, Pm_ws[(pbase + p) * CHUNK + mr]);
    float L = 0.f;
    float4 O; O.x = O.y = O.z = O.w = 0.f;
#pragma unroll 1
    for (int p = 0; p < nparts; ++p) {
        float f = __expf(Pm_ws[(pbase + p) * CHUNK + mr] - M);
        L += f * Pl_ws[(pbase + p) * CHUNK + mr];
        float4 po = *(const float4*)&Po_ws[((pbase + p) * CHUNK + mr) * HEAD + md];
        O.x += f * po.x; O.y += f * po.y; O.z += f * po.z; O.w += f * po.w;
    }
    float inv = 1.0f / L;
    float4 res; res.x = O.x * inv; res.y = O.y * inv; res.z = O.z * inv; res.w = O.w * inv;
    *(float4*)&out[(size_t)(b * SEQ + chunk * CHUNK + mr) * HEAD + md] = res;
}

extern "C" void kernel_launch(void* const* d_in, const int* in_sizes, int n_in,
                              void* d_out, int out_size, void* d_ws, size_t ws_size,
                              hipStream_t stream) {
    (void)in_sizes; (void)n_in; (void)out_size; (void)ws_size;
    const float* x  = (const float*)d_in[0];
    const float* wq = (const float*)d_in[1];
    const float* bq = (const float*)d_in[2];
    const float* wk = (const float*)d_in[3];
    const float* bk = (const float*)d_in[4];
    const float* wv = (const float*)d_in[5];
    const float* bv = (const float*)d_in[6];
    float* out = (float*)d_out;

    // workspace layout: 5.75 MB core + 8.5 MB partials = 14.25 MB (validated)
    ushort_t* Wfhi = (ushort_t*)d_ws;                        // 384 KB
    ushort_t* Wflo = Wfhi + (size_t)D_MODEL * 192;           // 384 KB
    ushort_t* Qhi  = Wflo + (size_t)D_MODEL * 192;           // 1 MB
    ushort_t* Qlo  = Qhi + (size_t)M_TOT * HEAD;             // 1 MB
    float*    Kw   = (float*)(Qlo + (size_t)M_TOT * HEAD);   // 2 MB fp32
    ushort_t* Vt   = (ushort_t*)(Kw + (size_t)M_TOT * HEAD); // 1 MB
    float* Pm_ws = (float*)(Vt + (size_t)M_TOT * HEAD);      // 128 KB
    float* Pl_ws = Pm_ws + (size_t)BATCH * 128 * NSEG * CHUNK;          // 128 KB
    float* Po_ws = Pl_ws + (size_t)BATCH * 128 * NSEG * CHUNK;          // 8 MB

    hipLaunchKernelGGL(wsplit_kernel, dim3(96), dim3(256), 0, stream,
                       wq, wk, wv, Wfhi, Wflo);
    hipLaunchKernelGGL(proj_kernel, dim3(M_TOT / 16 * 6 / 4), dim3(256), 0, stream,
                       x, Wfhi, Wflo, bq, bk, bv, Qhi, Qlo, Kw, Vt);
    hipLaunchKernelGGL(attn_part_kernel, dim3(320, BATCH), dim3(256),
                       0, stream, Qhi, Qlo, Kw, Vt, Pm_ws, Pl_ws, Po_ws);
    hipLaunchKernelGGL(attn_merge_kernel, dim3(SEQ / CHUNK, BATCH), dim3(256),
                       0, stream, Pm_ws, Pl_ws, Po_ws, out);
}

// Round 22
// 76.940 us; speedup vs baseline: 1.2928x; 1.2928x over previous
//
#include <hip/hip_runtime.h>
#include <math.h>

#define D_MODEL 1024
#define HEAD 64
#define BATCH 4
#define SEQ 2048
#define M_TOT (BATCH*SEQ)   // 8192

typedef short short8 __attribute__((ext_vector_type(8)));
typedef float f32x4 __attribute__((ext_vector_type(4)));
typedef unsigned short ushort_t;

typedef const __attribute__((address_space(1))) char* gas_t;
typedef __attribute__((address_space(3))) char* las_t;
#define GLDS16(src, dst) __builtin_amdgcn_global_load_lds((gas_t)(const void*)(src), (las_t)(void*)(dst), 16, 0, 0)

__device__ __forceinline__ unsigned short f2bf(float x) {       // round-to-nearest
    union { float f; unsigned u; } v; v.f = x;
    unsigned r = (v.u + 0x7FFFu + ((v.u >> 16) & 1u)) >> 16;
    return (unsigned short)r;
}
__device__ __forceinline__ unsigned short f2bf_trunc(float x) { // truncate mantissa
    union { float f; unsigned u; } v; v.f = x;
    return (unsigned short)(v.u >> 16);
}
__device__ __forceinline__ float bf2f(unsigned short h) {
    union { unsigned u; float f; } v; v.u = ((unsigned)h) << 16;
    return v.f;
}

// ---------------- W split prep (unchanged) ----------------
__global__ __launch_bounds__(256) void wsplit_kernel(
    const float* __restrict__ wq, const float* __restrict__ wk,
    const float* __restrict__ wv,
    ushort_t* __restrict__ Wfhi, ushort_t* __restrict__ Wflo)
{
    int tid = blockIdx.x * 256 + threadIdx.x;      // 0..24575
    int l = tid & 63;
    int c = l & 15, g = l >> 4;
    int rest = tid >> 6;
    int nt = rest % 12, ks = rest / 12;
    const float* W = (nt < 4) ? wq : ((nt < 8) ? wk : wv);
    int colm = ((nt & 3) * 16) + c;
    short8 hi, lo;
#pragma unroll
    for (int e = 0; e < 8; ++e) {
        float v = W[(size_t)(32 * ks + 8 * g + e) * HEAD + colm];
        unsigned short h = f2bf_trunc(v);
        hi[e] = (short)h;
        lo[e] = (short)f2bf(v - bf2f(h));
    }
    *(short8*)&Wfhi[(size_t)tid * 8] = hi;
    *(short8*)&Wflo[(size_t)tid * 8] = lo;
}

// ---------------- QKV projection v4 (R19 best: glds pipeline, depth-2) -----
// 4 waves/block, one 16-row m-tile; wave w computes nt 3w..3w+2. Same-block
// waves share x rows -> L2-local (R20's nt-pair split doubled HBM fetch).
// LDS slot (8 KB): [0,1K) xA, [1K,2K) xB, [2K,5K) Whi*3, [5K,8K) Wlo*3.
__global__ __launch_bounds__(256) void proj_kernel(
    const float* __restrict__ x,
    const ushort_t* __restrict__ Wfhi, const ushort_t* __restrict__ Wflo,
    const float* __restrict__ bq, const float* __restrict__ bk,
    const float* __restrict__ bv,
    ushort_t* __restrict__ Qhi, ushort_t* __restrict__ Qlo,
    float* __restrict__ Kw, ushort_t* __restrict__ Vt)
{
    __shared__ __align__(16) char pbuf[65536];   // 4 waves x 2 slots x 8 KB

    const int t = threadIdx.x;
    const int w = t >> 6;
    const int l = t & 63;
    const int c = l & 15, g = l >> 4;
    const int m0 = blockIdx.x * 16;

    char* wbase = pbuf + w * 16384;

    f32x4 acc[3];
#pragma unroll
    for (int j = 0; j < 3; ++j) acc[j] = (f32x4)0.0f;

    const float* xsrc = &x[(size_t)(m0 + c) * D_MODEL + 8 * g];

#define STAGE(i)                                                              \
    do {                                                                      \
        char* sb = wbase + ((i) & 1) * 8192;                                  \
        const float* xa = xsrc + (i) * 32;                                    \
        GLDS16(xa, sb);                                                       \
        GLDS16(xa + 4, sb + 1024);                                            \
        _Pragma("unroll")                                                     \
        for (int j = 0; j < 3; ++j) {                                         \
            const size_t wo = ((size_t)(i) * 12 + 3 * w + j) * 512 + l * 8;   \
            GLDS16(&Wfhi[wo], sb + 2048 + j * 1024);                          \
            GLDS16(&Wflo[wo], sb + 5120 + j * 1024);                          \
        }                                                                     \
    } while (0)

    STAGE(0);
    STAGE(1);

#pragma unroll 1
    for (int i = 0; i < 32; ++i) {
        if (i < 31) asm volatile("s_waitcnt vmcnt(8)" ::: "memory");
        else        asm volatile("s_waitcnt vmcnt(0)" ::: "memory");
        __builtin_amdgcn_sched_barrier(0);
        char* sb = wbase + (i & 1) * 8192;
        float4 fa = *(const float4*)(sb + l * 16);
        float4 fb = *(const float4*)(sb + 1024 + l * 16);
        float xs8[8] = {fa.x, fa.y, fa.z, fa.w, fb.x, fb.y, fb.z, fb.w};
        short8 xh, xl;
#pragma unroll
        for (int e = 0; e < 8; ++e) {
            unsigned short h = f2bf_trunc(xs8[e]);
            xh[e] = (short)h;
            xl[e] = (short)f2bf(xs8[e] - bf2f(h));
        }
#pragma unroll
        for (int j = 0; j < 3; ++j) {
            short8 wh = *(const short8*)(sb + 2048 + j * 1024 + l * 16);
            short8 wl_ = *(const short8*)(sb + 5120 + j * 1024 + l * 16);
            acc[j] = __builtin_amdgcn_mfma_f32_16x16x32_bf16(xh, wh, acc[j], 0, 0, 0);
            acc[j] = __builtin_amdgcn_mfma_f32_16x16x32_bf16(xl, wh, acc[j], 0, 0, 0);
            acc[j] = __builtin_amdgcn_mfma_f32_16x16x32_bf16(xh, wl_, acc[j], 0, 0, 0);
        }
        if (i < 30) STAGE(i + 2);
    }

    // epilogue: per-wave, aliased into the (now idle) pipeline LDS region
    float* eldw = (float*)wbase;            // [3][16][17]
#define ELD(j, r, cc) eldw[((j) * 16 + (r)) * 17 + (cc)]
#pragma unroll
    for (int j = 0; j < 3; ++j)
#pragma unroll
        for (int r = 0; r < 4; ++r)
            ELD(j, 4 * g + r, c) = acc[j][r];

    const int b = m0 >> 11;
    const int s0 = m0 & 2047;

#pragma unroll
    for (int j = 0; j < 3; ++j) {
        const int nt = 3 * w + j;
        const int col16 = (nt & 3) * 16;
        if (nt < 4) {
            const int row = l >> 2, cc4 = (l & 3) * 4;
            unsigned hu[2] = {0, 0}, lu[2] = {0, 0};
#pragma unroll
            for (int i = 0; i < 4; ++i) {
                float v = (ELD(j, row, cc4 + i) + bq[col16 + cc4 + i]) * 8.0f;
                unsigned short h = f2bf_trunc(v);
                unsigned short lo2 = f2bf(v - bf2f(h));
                hu[i >> 1] |= ((unsigned)h) << ((i & 1) * 16);
                lu[i >> 1] |= ((unsigned)lo2) << ((i & 1) * 16);
            }
            size_t off = (size_t)(m0 + row) * HEAD + col16 + cc4;
            *(uint2*)&Qhi[off] = make_uint2(hu[0], hu[1]);
            *(uint2*)&Qlo[off] = make_uint2(lu[0], lu[1]);
        } else if (nt < 8) {
            const int row = l >> 2, cc4 = (l & 3) * 4;
            float4 o;
            o.x = ELD(j, row, cc4 + 0) + bk[col16 + cc4 + 0];
            o.y = ELD(j, row, cc4 + 1) + bk[col16 + cc4 + 1];
            o.z = ELD(j, row, cc4 + 2) + bk[col16 + cc4 + 2];
            o.w = ELD(j, row, cc4 + 3) + bk[col16 + cc4 + 3];
            *(float4*)&Kw[(size_t)(m0 + row) * HEAD + col16 + cc4] = o;
        } else {
            const int dl = l >> 2, sg = (l & 3) * 4;
            const float bb = bv[col16 + dl];
            unsigned vu[2] = {0, 0};
#pragma unroll
            for (int i = 0; i < 4; ++i) {
                unsigned short v = f2bf(ELD(j, sg + i, dl) + bb);
                vu[i >> 1] |= ((unsigned)v) << ((i & 1) * 16);
            }
            *(uint2*)&Vt[((size_t)b * HEAD + col16 + dl) * SEQ + s0 + sg] =
                make_uint2(vu[0], vu[1]);
        }
    }
#undef ELD
#undef STAGE
}

// ---------------- Flash causal attention v8 (unchanged from R18) -----------
#define NW 4
#define CHUNK 16
#define PSTR 72
#define NSEG 4          // segments of 512 kv positions (8 tiles)

__global__ __launch_bounds__(256) void attn_part_kernel(
    const ushort_t* __restrict__ Qhi, const ushort_t* __restrict__ Qlo,
    const float* __restrict__ Kw, const ushort_t* __restrict__ Vt,
    float* __restrict__ Pm_ws, float* __restrict__ Pl_ws,
    float* __restrict__ Po_ws)
{
    __shared__ float Po[NW][CHUNK][68];
    __shared__ float Pm[NW][CHUNK];
    __shared__ float Pl[NW][CHUNK];
    __shared__ __align__(16) ushort_t Plds[NW][CHUNK][PSTR];

    const int t = threadIdx.x;
    const int w = t >> 6;
    const int l = t & 63;
    int id = blockIdx.x;
    int seg, base;
    if (id < 128)      { seg = 0; base = 0;   }
    else if (id < 224) { seg = 1; base = 128; }
    else if (id < 288) { seg = 2; base = 224; }
    else               { seg = 3; base = 288; }
    const int chunk = 127 - (id - base);
    const int b = blockIdx.y;
    const int q0 = chunk * CHUNK;

    const int c = l & 15;
    const int g = l >> 4;

    short8 qhi[2], qlo[2];
    {
        const ushort_t* qbase = &Qhi[(size_t)(b * SEQ + q0 + c) * HEAD];
        const ushort_t* qbasel = &Qlo[(size_t)(b * SEQ + q0 + c) * HEAD];
#pragma unroll
        for (int dc = 0; dc < 2; ++dc) {
            qhi[dc] = *(const short8*)&qbase[dc * 32 + 8 * g];
            qlo[dc] = *(const short8*)&qbasel[dc * 32 + 8 * g];
        }
    }

    f32x4 acc[4];
#pragma unroll
    for (int dt = 0; dt < 4; ++dt) acc[dt] = (f32x4)0.0f;
    float mrun = -1e30f, lsum = 0.f;

#pragma unroll 1
    for (int i = 0; i < 2; ++i) {
        const int tl = seg * 8 + w + 4 * i;
        const int c0 = tl * 64;
        if (c0 > q0 + CHUNK - 1) continue;

        int nlive = ((q0 + 15 - c0) >> 4) + 1;
        nlive = nlive > 4 ? 4 : nlive;

        float sc[4][4];
        float tmax = -1e30f;
#pragma unroll
        for (int t4 = 0; t4 < 4; ++t4) {
            if (t4 < nlive) {
                f32x4 st = (f32x4)0.0f;
#pragma unroll
                for (int dc = 0; dc < 2; ++dc) {
                    const float* kp = &Kw[(size_t)(b * SEQ + c0 + 16 * t4 + c) * HEAD + dc * 32 + 8 * g];
                    float4 a = *(const float4*)kp;
                    float4 b2 = *(const float4*)(kp + 4);
                    float ks8[8] = {a.x, a.y, a.z, a.w, b2.x, b2.y, b2.z, b2.w};
                    short8 khi, klo;
#pragma unroll
                    for (int e = 0; e < 8; ++e) {
                        unsigned short h = f2bf(ks8[e]);
                        khi[e] = (short)h;
                        klo[e] = (short)f2bf(ks8[e] - bf2f(h));
                    }
                    st = __builtin_amdgcn_mfma_f32_16x16x32_bf16(khi, qhi[dc], st, 0, 0, 0);
                    st = __builtin_amdgcn_mfma_f32_16x16x32_bf16(khi, qlo[dc], st, 0, 0, 0);
                    st = __builtin_amdgcn_mfma_f32_16x16x32_bf16(klo, qhi[dc], st, 0, 0, 0);
                }
#pragma unroll
                for (int r = 0; r < 4; ++r) {
                    int kv = c0 + 16 * t4 + 4 * g + r;
                    float s = (kv <= q0 + c) ? st[r] : -1e30f;
                    sc[t4][r] = s;
                    tmax = fmaxf(tmax, s);
                }
            } else {
#pragma unroll
                for (int r = 0; r < 4; ++r) sc[t4][r] = -1e30f;
            }
        }
        tmax = fmaxf(tmax, __shfl_xor(tmax, 16));
        tmax = fmaxf(tmax, __shfl_xor(tmax, 32));
        float newm = fmaxf(mrun, tmax);
        float corr = __expf(mrun - newm);
        mrun = newm;

        float psum = 0.f;
#pragma unroll
        for (int t4 = 0; t4 < 4; ++t4) {
            if (t4 < nlive) {
#pragma unroll
                for (int r = 0; r < 4; ++r) {
                    float pp = __expf(sc[t4][r] - newm);
                    sc[t4][r] = pp;
                    psum += pp;
                }
            } else {
#pragma unroll
                for (int r = 0; r < 4; ++r) sc[t4][r] = 0.f;
            }
        }
        psum += __shfl_xor(psum, 16);
        psum += __shfl_xor(psum, 32);
        lsum = lsum * corr + psum;

#pragma unroll
        for (int r = 0; r < 4; ++r) {
            float cq = __shfl(corr, 4 * g + r);
#pragma unroll
            for (int dt = 0; dt < 4; ++dt) acc[dt][r] *= cq;
        }

#pragma unroll
        for (int t4 = 0; t4 < 4; ++t4) {
            uint2 u;
            u.x = (unsigned)f2bf(sc[t4][0]) | ((unsigned)f2bf(sc[t4][1]) << 16);
            u.y = (unsigned)f2bf(sc[t4][2]) | ((unsigned)f2bf(sc[t4][3]) << 16);
            *(uint2*)&Plds[w][c][16 * t4 + 4 * g] = u;
        }
        const int nkvc = (nlive + 1) >> 1;
#pragma unroll
        for (int kvc = 0; kvc < 2; ++kvc) {
            if (kvc < nkvc) {
                short8 pf = *(short8*)&Plds[w][c][kvc * 32 + 8 * g];
#pragma unroll
                for (int dt = 0; dt < 4; ++dt) {
                    const ushort_t* vp =
                        &Vt[((size_t)(b * HEAD) + 16 * dt + c) * SEQ + c0 + kvc * 32 + 8 * g];
                    short8 vf = *(const short8*)vp;
                    acc[dt] = __builtin_amdgcn_mfma_f32_16x16x32_bf16(pf, vf, acc[dt], 0, 0, 0);
                }
            }
        }
    }

    if (g == 0) { Pm[w][c] = mrun; Pl[w][c] = lsum; }
#pragma unroll
    for (int dt = 0; dt < 4; ++dt)
#pragma unroll
        for (int r = 0; r < 4; ++r)
            Po[w][4 * g + r][16 * dt + c] = acc[dt][r];
    __syncthreads();

    const int mr = t >> 4;
    const int md = (t & 15) * 4;
    float M = Pm[0][mr];
#pragma unroll
    for (int ww = 1; ww < NW; ++ww) M = fmaxf(M, Pm[ww][mr]);
    float L = 0.f;
    float4 O; O.x = O.y = O.z = O.w = 0.f;
#pragma unroll
    for (int ww = 0; ww < NW; ++ww) {
        float f = __expf(Pm[ww][mr] - M);
        L += f * Pl[ww][mr];
        float4 p = *(const float4*)&Po[ww][mr][md];
        O.x += f * p.x; O.y += f * p.y; O.z += f * p.z; O.w += f * p.w;
    }
    const size_t part = ((size_t)(b * 128 + chunk)) * NSEG + seg;
    *(float4*)&Po_ws[(part * CHUNK + mr) * HEAD + md] = O;
    if ((t & 15) == 0) {
        Pm_ws[part * CHUNK + mr] = M;
        Pl_ws[part * CHUNK + mr] = L;
    }
}

__global__ __launch_bounds__(256) void attn_merge_kernel(
    const float* __restrict__ Pm_ws, const float* __restrict__ Pl_ws,
    const float* __restrict__ Po_ws, float* __restrict__ out)
{
    const int t = threadIdx.x;
    const int chunk = blockIdx.x;
    const int b = blockIdx.y;
    const int nparts = (chunk >> 5) + 1;
    const int mr = t >> 4;
    const int md = (t & 15) * 4;
    const size_t pbase = ((size_t)(b * 128 + chunk)) * NSEG;

    float M = -1e30f;
#pragma unroll 1
    for (int p = 0; p < nparts; ++p)
        M = fmaxf(M, Pm_ws[(pbase + p) * CHUNK + mr]);
    float L = 0.f;
    float4 O; O.x = O.y = O.z = O.w = 0.f;
#pragma unroll 1
    for (int p = 0; p < nparts; ++p) {
        float f = __expf(Pm_ws[(pbase + p) * CHUNK + mr] - M);
        L += f * Pl_ws[(pbase + p) * CHUNK + mr];
        float4 po = *(const float4*)&Po_ws[((pbase + p) * CHUNK + mr) * HEAD + md];
        O.x += f * po.x; O.y += f * po.y; O.z += f * po.z; O.w += f * po.w;
    }
    float inv = 1.0f / L;
    float4 res; res.x = O.x * inv; res.y = O.y * inv; res.z = O.z * inv; res.w = O.w * inv;
    *(float4*)&out[(size_t)(b * SEQ + chunk * CHUNK + mr) * HEAD + md] = res;
}

extern "C" void kernel_launch(void* const* d_in, const int* in_sizes, int n_in,
                              void* d_out, int out_size, void* d_ws, size_t ws_size,
                              hipStream_t stream) {
    (void)in_sizes; (void)n_in; (void)out_size; (void)ws_size;
    const float* x  = (const float*)d_in[0];
    const float* wq = (const float*)d_in[1];
    const float* bq = (const float*)d_in[2];
    const float* wk = (const float*)d_in[3];
    const float* bk = (const float*)d_in[4];
    const float* wv = (const float*)d_in[5];
    const float* bv = (const float*)d_in[6];
    float* out = (float*)d_out;

    // workspace layout: 5.75 MB core + 8.5 MB partials = 14.25 MB (validated)
    ushort_t* Wfhi = (ushort_t*)d_ws;                        // 384 KB
    ushort_t* Wflo = Wfhi + (size_t)D_MODEL * 192;           // 384 KB
    ushort_t* Qhi  = Wflo + (size_t)D_MODEL * 192;           // 1 MB
    ushort_t* Qlo  = Qhi + (size_t)M_TOT * HEAD;             // 1 MB
    float*    Kw   = (float*)(Qlo + (size_t)M_TOT * HEAD);   // 2 MB fp32
    ushort_t* Vt   = (ushort_t*)(Kw + (size_t)M_TOT * HEAD); // 1 MB
    float* Pm_ws = (float*)(Vt + (size_t)M_TOT * HEAD);      // 128 KB
    float* Pl_ws = Pm_ws + (size_t)BATCH * 128 * NSEG * CHUNK;          // 128 KB
    float* Po_ws = Pl_ws + (size_t)BATCH * 128 * NSEG * CHUNK;          // 8 MB

    hipLaunchKernelGGL(wsplit_kernel, dim3(96), dim3(256), 0, stream,
                       wq, wk, wv, Wfhi, Wflo);
    hipLaunchKernelGGL(proj_kernel, dim3(M_TOT / 16), dim3(256), 0, stream,
                       x, Wfhi, Wflo, bq, bk, bv, Qhi, Qlo, Kw, Vt);
    hipLaunchKernelGGL(attn_part_kernel, dim3(320, BATCH), dim3(256),
                       0, stream, Qhi, Qlo, Kw, Vt, Pm_ws, Pl_ws, Po_ws);
    hipLaunchKernelGGL(attn_merge_kernel, dim3(SEQ / CHUNK, BATCH), dim3(256),
                       0, stream, Pm_ws, Pl_ws, Po_ws, out);
}